// Round 5
// baseline (259.490 us; speedup 1.0000x reference)
//
#include <hip/hip_runtime.h>
#include <hip/hip_bf16.h>
#include <math.h>

#define BDIM 2
#define NDIM 512
#define HID 768
#define BIAF 256
#define CLS 14
#define DD 257   // BIAF+1
#define NPOS 30
#define SDIM 25
#define HSZ 539  // 2*257+25
#define PK 288   // padded contraction length (i and j), 9*32
#define PJ 384   // packW j-rows padding

typedef unsigned short ushort_t;
typedef __attribute__((ext_vector_type(8))) short short8;   // 8 bf16
typedef __attribute__((ext_vector_type(4))) float floatx4;  // 4 f32

#define MFMA16(a, b, c) __builtin_amdgcn_mfma_f32_16x16x32_bf16((a), (b), (c), 0, 0, 0)

__device__ inline float bf2f(ushort_t u) {
    union { unsigned int i; float f; } c; c.i = ((unsigned)u) << 16; return c.f;
}
__device__ inline ushort_t f2bf(float f) {
    __hip_bfloat16 h = __float2bfloat16(f);
    return *(ushort_t*)&h;
}

// split 8 f32 into hi/lo bf16 frags
__device__ inline void split8(const float* v, short8& hi, short8& lo) {
    #pragma unroll
    for (int j = 0; j < 8; ++j) {
        ushort_t h = f2bf(v[j]);
        float hf = bf2f(h);
        ((short*)&hi)[j] = (short)h;
        ((short*)&lo)[j] = (short)f2bf(v[j] - hf);
    }
}

// ---------------------------------------------------------------------------
// repack_t: packW[k][j][i] = bf16(biafW[k][i][j]), zero-padded to PJ x PK
// ---------------------------------------------------------------------------
__global__ __launch_bounds__(256) void repack_t(
    const float* __restrict__ biafW, ushort_t* __restrict__ packW)
{
    __shared__ float tile[32][33];
    const int i0 = blockIdx.x * 32;
    const int j0 = blockIdx.y * 32;
    const int k  = blockIdx.z;
    const int r8 = threadIdx.x >> 5;   // 0..7
    const int c  = threadIdx.x & 31;
    #pragma unroll
    for (int rr = 0; rr < 4; ++rr) {
        int r = rr * 8 + r8;
        int gi = i0 + r, gj = j0 + c;
        tile[r][c] = (gi < DD && gj < DD) ? biafW[((size_t)k * DD + gi) * DD + gj] : 0.f;
    }
    __syncthreads();
    #pragma unroll
    for (int rr = 0; rr < 4; ++rr) {
        int jr = rr * 8 + r8;
        packW[((size_t)k * PJ + (j0 + jr)) * PK + i0 + c] = f2bf(tile[c][jr]);
    }
}

// ---------------------------------------------------------------------------
// wsplit: hi/lo bf16 planes of the 4 projection weight matrices
// layout: plane[mat][256][768], mat = {m1w, m2w, hw, tw}
// ---------------------------------------------------------------------------
__global__ __launch_bounds__(256) void wsplit(
    const float* __restrict__ m1w, const float* __restrict__ m2w,
    const float* __restrict__ hw,  const float* __restrict__ tw,
    ushort_t* __restrict__ whi, ushort_t* __restrict__ wlo)
{
    int idx = blockIdx.x * 256 + threadIdx.x;      // 786432 items
    int mat = idx / (BIAF * HID);
    int rem = idx % (BIAF * HID);
    const float* src = (mat == 0) ? m1w : (mat == 1) ? m2w : (mat == 2) ? hw : tw;
    float v = src[rem];
    ushort_t h = f2bf(v);
    whi[idx] = h;
    wlo[idx] = f2bf(v - bf2f(h));
}

// ---------------------------------------------------------------------------
// fill pad columns of h1/t1 hi/lo planes: col 256 = 1.0(hi)/0(lo), 257..287 = 0
// ---------------------------------------------------------------------------
__global__ void fill_pads(ushort_t* __restrict__ h1hi, ushort_t* __restrict__ h1lo,
                          ushort_t* __restrict__ t1hi, ushort_t* __restrict__ t1lo) {
    int idx = blockIdx.x * 256 + threadIdx.x;          // 131072 items
    int plane = idx >> 15;                             // 0..3
    int tok = (idx >> 5) & 1023;
    int c   = 256 + (idx & 31);
    ushort_t* dst = (plane == 0) ? h1hi : (plane == 1) ? h1lo : (plane == 2) ? t1hi : t1lo;
    ushort_t val = (c == 256 && (plane == 0 || plane == 2)) ? (ushort_t)0x3F80 : (ushort_t)0;
    dst[(size_t)tok * PK + c] = val;
}

// ---------------------------------------------------------------------------
// proj_mfma: 4 projections, pre-split weights, 3-term split MFMA
// grid 256: proj = bx>>6, mt = (bx>>2)&15, ft = bx&3
// ---------------------------------------------------------------------------
__global__ __launch_bounds__(256) void proj_mfma(
    const float* __restrict__ x, const float* __restrict__ y,
    const ushort_t* __restrict__ whi, const ushort_t* __restrict__ wlo,
    const float* __restrict__ m1b, const float* __restrict__ m2b,
    const float* __restrict__ hb,  const float* __restrict__ tb,
    ushort_t* __restrict__ h1hi, ushort_t* __restrict__ h1lo,
    ushort_t* __restrict__ t1hi, ushort_t* __restrict__ t1lo,
    float* __restrict__ headf, float* __restrict__ tailf)
{
    const int bx = blockIdx.x;
    const int proj = bx >> 6;
    const int mt = (bx >> 2) & 15;
    const int ft = bx & 3;
    const int wave = threadIdx.x >> 6, L = threadIdx.x & 63;
    const int quad = L >> 4, l16 = L & 15;
    const int m0w = mt * 64 + wave * 16;
    const int f0 = ft * 64;

    const float* src  = (proj == 1) ? y : x;
    const float* bias = (proj == 0) ? m1b : (proj == 1) ? m2b : (proj == 2) ? hb : tb;

    const float* arow = src + (size_t)(m0w + l16) * HID + quad * 8;
    const size_t wbase = (size_t)proj * BIAF * HID;

    floatx4 acc[4];
    #pragma unroll
    for (int nf = 0; nf < 4; ++nf)
        #pragma unroll
        for (int r = 0; r < 4; ++r) acc[nf][r] = 0.f;

    for (int k0 = 0; k0 < HID; k0 += 32) {
        float av[8];
        *(float4*)&av[0] = *(const float4*)(arow + k0);
        *(float4*)&av[4] = *(const float4*)(arow + k0 + 4);
        short8 ahi, alo;
        split8(av, ahi, alo);
        #pragma unroll
        for (int nf = 0; nf < 4; ++nf) {
            size_t boff = wbase + (size_t)(f0 + nf * 16 + l16) * HID + quad * 8 + k0;
            short8 bhi = *(const short8*)(whi + boff);
            short8 blo = *(const short8*)(wlo + boff);
            acc[nf] = MFMA16(ahi, bhi, acc[nf]);
            acc[nf] = MFMA16(alo, bhi, acc[nf]);
            acc[nf] = MFMA16(ahi, blo, acc[nf]);
        }
    }

    #pragma unroll
    for (int nf = 0; nf < 4; ++nf) {
        int feat = f0 + nf * 16 + l16;
        float bv = bias[feat];
        #pragma unroll
        for (int r = 0; r < 4; ++r) {
            int tok = m0w + quad * 4 + r;
            float v = acc[nf][r] + bv;
            if (proj == 0) {
                float g = 0.5f * v * (1.0f + erff(v * 0.70710678118654752f));
                ushort_t h = f2bf(g);
                h1hi[(size_t)tok * PK + feat] = h;
                h1lo[(size_t)tok * PK + feat] = f2bf(g - bf2f(h));
            } else if (proj == 1) {
                float g = 0.5f * v * (1.0f + erff(v * 0.70710678118654752f));
                ushort_t h = f2bf(g);
                t1hi[(size_t)tok * PK + feat] = h;
                t1lo[(size_t)tok * PK + feat] = f2bf(g - bf2f(h));
            } else if (proj == 2) {
                headf[(size_t)tok * 256 + feat] = (v >= 0.f) ? v : 0.01f * v;
            } else {
                tailf[(size_t)tok * 256 + feat] = (v >= 0.f) ? v : 0.01f * v;
            }
        }
    }
}

// ---------------------------------------------------------------------------
// hk[b][k][m] = dot(headf[tok], Wh[k]) + Wh[k][256]; tk likewise with Wt
// ---------------------------------------------------------------------------
__global__ __launch_bounds__(256) void hk_tk_kernel(
    const float* __restrict__ headf, const float* __restrict__ tailf,
    const float* __restrict__ W,
    float* __restrict__ hk, float* __restrict__ tk)
{
    int p = blockIdx.x * 256 + threadIdx.x;  // 32768 items
    int which = p >> 14;                     // 0=hk, 1=tk
    int idx = p & 16383;
    int tok = idx >> 4;
    int k = idx & 15;
    if (k >= CLS) return;
    const float* row = (which ? tailf : headf) + (size_t)tok * 256;
    const float* wr = W + (size_t)k * HSZ + (which ? DD : 0);
    float acc = 0.f;
    for (int f4 = 0; f4 < 64; ++f4) {
        float4 rv = *(const float4*)(row + f4 * 4);
        acc += rv.x * wr[f4*4] + rv.y * wr[f4*4+1] + rv.z * wr[f4*4+2] + rv.w * wr[f4*4+3];
    }
    acc += wr[256];
    float* dst = which ? tk : hk;
    dst[(size_t)(tok >> 9) * CLS * NDIM + (size_t)k * NDIM + (tok & 511)] = acc;
}

// ---------------------------------------------------------------------------
// sk[k][d] = sum_h size_emb[d][h] * Ws[k][h]
// ---------------------------------------------------------------------------
__global__ void sk_kernel(const float* __restrict__ semb, const float* __restrict__ W,
                          float* __restrict__ sk)
{
    int idx = blockIdx.x * 256 + threadIdx.x;
    if (idx < CLS * NPOS) {
        int k = idx / NPOS, d = idx % NPOS;
        float acc = 0.f;
        for (int h = 0; h < SDIM; ++h)
            acc += semb[d*SDIM + h] * W[k*HSZ + 2*DD + h];
        sk[idx] = acc;
    }
}

// ---------------------------------------------------------------------------
// fused_out: per (b,k,m-tile of 64):
//   phase 1: A[64][288] = h1[m-tile] @ biafW[k]  (2-term split) -> bf16 LDS
//   phase 2: out[m-tile][n] = A @ t1^T (2-term) + hk + tk + sk
// grid (8 mt, 28 bk), 256 thr (4 waves; phase2: wave w owns n in [w*128, w*128+128))
// ---------------------------------------------------------------------------
__global__ __launch_bounds__(256) void fused_out(
    const ushort_t* __restrict__ h1hi, const ushort_t* __restrict__ h1lo,
    const ushort_t* __restrict__ packW,
    const ushort_t* __restrict__ t1hi, const ushort_t* __restrict__ t1lo,
    const float* __restrict__ hk, const float* __restrict__ tk,
    const float* __restrict__ sk,
    float* __restrict__ out)
{
    __shared__ ushort_t Alds[64][PK];   // 36864 B
    __shared__ float skr[NPOS];
    const int mt = blockIdx.x, bk = blockIdx.y;
    const int b = bk / CLS, k = bk % CLS;
    const int wave = threadIdx.x >> 6, L = threadIdx.x & 63;
    const int quad = L >> 4, l16 = L & 15;
    const int m0 = mt * 64;
    if (threadIdx.x < NPOS) skr[threadIdx.x] = sk[k * NPOS + threadIdx.x];

    // ---- phase 1: A-tile ----
    {
        const size_t h1base = (size_t)b * NDIM * PK;
        const ushort_t* BT = packW + (size_t)k * PJ * PK;
        size_t aoff[4];
        #pragma unroll
        for (int mi = 0; mi < 4; ++mi)
            aoff[mi] = h1base + (size_t)(m0 + mi * 16 + l16) * PK + quad * 8;

        // wave handles j-frags jf = wave, wave+4, ... (< 18): 5,5,4,4
        int jfs[5]; int njf = 0;
        for (int jf = wave; jf < 18; jf += 4) jfs[njf++] = jf;

        floatx4 acc1[4][5];
        #pragma unroll
        for (int mi = 0; mi < 4; ++mi)
            #pragma unroll
            for (int jj = 0; jj < 5; ++jj)
                #pragma unroll
                for (int r = 0; r < 4; ++r) acc1[mi][jj][r] = 0.f;

        for (int k0 = 0; k0 < PK; k0 += 32) {
            short8 ahi[4], alo[4];
            #pragma unroll
            for (int mi = 0; mi < 4; ++mi) {
                ahi[mi] = *(const short8*)(h1hi + aoff[mi] + k0);
                alo[mi] = *(const short8*)(h1lo + aoff[mi] + k0);
            }
            for (int jj = 0; jj < njf; ++jj) {
                short8 bb = *(const short8*)(BT + (size_t)(jfs[jj] * 16 + l16) * PK + quad * 8 + k0);
                #pragma unroll
                for (int mi = 0; mi < 4; ++mi) {
                    acc1[mi][jj] = MFMA16(ahi[mi], bb, acc1[mi][jj]);
                    acc1[mi][jj] = MFMA16(alo[mi], bb, acc1[mi][jj]);
                }
            }
        }
        for (int jj = 0; jj < njf; ++jj) {
            int j0 = jfs[jj] * 16;
            #pragma unroll
            for (int mi = 0; mi < 4; ++mi)
                #pragma unroll
                for (int r = 0; r < 4; ++r)
                    Alds[mi * 16 + quad * 4 + r][j0 + l16] = f2bf(acc1[mi][jj][r]);
        }
    }
    __syncthreads();

    // ---- phase 2: out-tile, wave w covers n in [w*128, (w+1)*128) ----
    const int n0 = wave * 128;
    const size_t tbase = (size_t)b * NDIM * PK;
    size_t boff[8];
    #pragma unroll
    for (int nf = 0; nf < 8; ++nf)
        boff[nf] = tbase + (size_t)(n0 + nf * 16 + l16) * PK + quad * 8;

    floatx4 acc2[4][8];
    #pragma unroll
    for (int mi = 0; mi < 4; ++mi)
        #pragma unroll
        for (int nf = 0; nf < 8; ++nf)
            #pragma unroll
            for (int r = 0; r < 4; ++r) acc2[mi][nf][r] = 0.f;

    for (int k0 = 0; k0 < PK; k0 += 32) {
        short8 a[4];
        #pragma unroll
        for (int mi = 0; mi < 4; ++mi)
            a[mi] = *(const short8*)&Alds[mi * 16 + l16][k0 + quad * 8];
        // hi pass
        {
            short8 bh[8];
            #pragma unroll
            for (int nf = 0; nf < 8; ++nf) bh[nf] = *(const short8*)(t1hi + boff[nf] + k0);
            #pragma unroll
            for (int mi = 0; mi < 4; ++mi)
                #pragma unroll
                for (int nf = 0; nf < 8; ++nf)
                    acc2[mi][nf] = MFMA16(a[mi], bh[nf], acc2[mi][nf]);
        }
        // lo pass
        {
            short8 bl[8];
            #pragma unroll
            for (int nf = 0; nf < 8; ++nf) bl[nf] = *(const short8*)(t1lo + boff[nf] + k0);
            #pragma unroll
            for (int mi = 0; mi < 4; ++mi)
                #pragma unroll
                for (int nf = 0; nf < 8; ++nf)
                    acc2[mi][nf] = MFMA16(a[mi], bl[nf], acc2[mi][nf]);
        }
    }

    const size_t obase = (size_t)bk * NDIM;
    #pragma unroll
    for (int mi = 0; mi < 4; ++mi) {
        #pragma unroll
        for (int r = 0; r < 4; ++r) {
            int row = m0 + mi * 16 + quad * 4 + r;
            float hv = hk[obase + row];
            #pragma unroll
            for (int nf = 0; nf < 8; ++nf) {
                int col = n0 + nf * 16 + l16;
                int d = col - row; d = d < -15 ? -15 : (d > 14 ? 14 : d); d += 15;
                out[(obase + row) * NDIM + col] = acc2[mi][nf][r] + hv + tk[obase + col] + skr[d];
            }
        }
    }
}

// ---------------------------------------------------------------------------
extern "C" void kernel_launch(void* const* d_in, const int* in_sizes, int n_in,
                              void* d_out, int out_size, void* d_ws, size_t ws_size,
                              hipStream_t stream) {
    const float* x    = (const float*)d_in[0];
    const float* y    = (const float*)d_in[1];
    // d_in[2] = z : unused
    const float* m1w  = (const float*)d_in[3];
    const float* m1b  = (const float*)d_in[4];
    const float* m2w  = (const float*)d_in[5];
    const float* m2b  = (const float*)d_in[6];
    const float* hw   = (const float*)d_in[7];
    const float* hb   = (const float*)d_in[8];
    const float* tw   = (const float*)d_in[9];
    const float* tb   = (const float*)d_in[10];
    const float* biafW= (const float*)d_in[11];
    const float* W    = (const float*)d_in[12];
    const float* semb = (const float*)d_in[13];

    char* p = (char*)d_ws;
    float* hk   = (float*)p;                    p += 57344;
    float* tk   = (float*)p;                    p += 57344;
    float* skp  = (float*)p;                    p += 2048;
    float* headf= (float*)p;                    p += 1048576;
    float* tailf= (float*)p;                    p += 1048576;
    ushort_t* h1hi = (ushort_t*)p;              p += 589824;
    ushort_t* h1lo = (ushort_t*)p;              p += 589824;
    ushort_t* t1hi = (ushort_t*)p;              p += 589824;
    ushort_t* t1lo = (ushort_t*)p;              p += 589824;
    ushort_t* packW= (ushort_t*)p;              p += 3096576;  // 14*384*288*2
    ushort_t* whi  = (ushort_t*)p;              p += 1572864;  // 4*256*768*2
    ushort_t* wlo  = (ushort_t*)p;              p += 1572864;

    repack_t<<<dim3(9, 12, CLS), 256, 0, stream>>>(biafW, packW);
    wsplit<<<3072, 256, 0, stream>>>(m1w, m2w, hw, tw, whi, wlo);
    fill_pads<<<512, 256, 0, stream>>>(h1hi, h1lo, t1hi, t1lo);
    proj_mfma<<<256, 256, 0, stream>>>(x, y, whi, wlo, m1b, m2b, hb, tb,
                                       h1hi, h1lo, t1hi, t1lo, headf, tailf);
    hk_tk_kernel<<<128, 256, 0, stream>>>(headf, tailf, W, hk, tk);
    sk_kernel<<<2, 256, 0, stream>>>(semb, W, skp);
    fused_out<<<dim3(8, BDIM*CLS), 256, 0, stream>>>(h1hi, h1lo, packW, t1hi, t1lo,
                                                     hk, tk, skp, (float*)d_out);
}

// Round 6
// 214.459 us; speedup vs baseline: 1.2100x; 1.2100x over previous
//
#include <hip/hip_runtime.h>
#include <hip/hip_bf16.h>
#include <math.h>

#define BDIM 2
#define NDIM 512
#define HID 768
#define BIAF 256
#define CLS 14
#define DD 257   // BIAF+1
#define NPOS 30
#define SDIM 25
#define HSZ 539  // 2*257+25
#define PK 288   // padded contraction length (i and j), 9*32
#define PJ 384   // packW j-rows padding
#define LDW 40   // LDS tile row stride in ushorts (80 B = 5*16B, kills 8-way conflicts)

typedef unsigned short ushort_t;
typedef __attribute__((ext_vector_type(8))) short short8;   // 8 bf16
typedef __attribute__((ext_vector_type(4))) float floatx4;  // 4 f32

#define MFMA16(a, b, c) __builtin_amdgcn_mfma_f32_16x16x32_bf16((a), (b), (c), 0, 0, 0)

__device__ inline float bf2f(ushort_t u) {
    union { unsigned int i; float f; } c; c.i = ((unsigned)u) << 16; return c.f;
}
__device__ inline ushort_t f2bf(float f) {
    __hip_bfloat16 h = __float2bfloat16(f);
    return *(ushort_t*)&h;
}

// split 8 f32 into hi/lo bf16 frags
__device__ inline void split8(const float* v, short8& hi, short8& lo) {
    #pragma unroll
    for (int j = 0; j < 8; ++j) {
        ushort_t h = f2bf(v[j]);
        float hf = bf2f(h);
        ((short*)&hi)[j] = (short)h;
        ((short*)&lo)[j] = (short)f2bf(v[j] - hf);
    }
}

// stage one 128x32 bf16 tile (rows from global, row stride gstride elems) into
// LDS tile with row stride LDW ushorts. 256 threads, 2 x 16B per thread.
__device__ inline void stage_tile(const ushort_t* __restrict__ g, size_t gstride,
                                  ushort_t* __restrict__ lds, int tid) {
    int r0 = tid >> 2, c4 = tid & 3;
    #pragma unroll
    for (int i = 0; i < 2; ++i) {
        int row = i * 64 + r0;
        uint4 v = *(const uint4*)(g + (size_t)row * gstride + c4 * 8);
        *(uint4*)(lds + row * LDW + c4 * 8) = v;
    }
}

// ---------------------------------------------------------------------------
// repack_t: packW[k][j][i] = bf16(biafW[k][i][j]), zero-padded to PJ x PK
// ---------------------------------------------------------------------------
__global__ __launch_bounds__(256) void repack_t(
    const float* __restrict__ biafW, ushort_t* __restrict__ packW)
{
    __shared__ float tile[32][33];
    const int i0 = blockIdx.x * 32;
    const int j0 = blockIdx.y * 32;
    const int k  = blockIdx.z;
    const int r8 = threadIdx.x >> 5;   // 0..7
    const int c  = threadIdx.x & 31;
    #pragma unroll
    for (int rr = 0; rr < 4; ++rr) {
        int r = rr * 8 + r8;
        int gi = i0 + r, gj = j0 + c;
        tile[r][c] = (gi < DD && gj < DD) ? biafW[((size_t)k * DD + gi) * DD + gj] : 0.f;
    }
    __syncthreads();
    #pragma unroll
    for (int rr = 0; rr < 4; ++rr) {
        int jr = rr * 8 + r8;
        packW[((size_t)k * PJ + (j0 + jr)) * PK + i0 + c] = f2bf(tile[c][jr]);
    }
}

// ---------------------------------------------------------------------------
// wsplit: hi/lo bf16 planes of the 4 projection weight matrices
// ---------------------------------------------------------------------------
__global__ __launch_bounds__(256) void wsplit(
    const float* __restrict__ m1w, const float* __restrict__ m2w,
    const float* __restrict__ hw,  const float* __restrict__ tw,
    ushort_t* __restrict__ whi, ushort_t* __restrict__ wlo)
{
    int idx = blockIdx.x * 256 + threadIdx.x;      // 786432 items
    int mat = idx / (BIAF * HID);
    int rem = idx % (BIAF * HID);
    const float* src = (mat == 0) ? m1w : (mat == 1) ? m2w : (mat == 2) ? hw : tw;
    float v = src[rem];
    ushort_t h = f2bf(v);
    whi[idx] = h;
    wlo[idx] = f2bf(v - bf2f(h));
}

// ---------------------------------------------------------------------------
// fill pad columns of h1/t1 hi/lo planes: col 256 = 1.0(hi)/0(lo), 257..287 = 0
// ---------------------------------------------------------------------------
__global__ void fill_pads(ushort_t* __restrict__ h1hi, ushort_t* __restrict__ h1lo,
                          ushort_t* __restrict__ t1hi, ushort_t* __restrict__ t1lo) {
    int idx = blockIdx.x * 256 + threadIdx.x;          // 131072 items
    int plane = idx >> 15;                             // 0..3
    int tok = (idx >> 5) & 1023;
    int c   = 256 + (idx & 31);
    ushort_t* dst = (plane == 0) ? h1hi : (plane == 1) ? h1lo : (plane == 2) ? t1hi : t1lo;
    ushort_t val = (c == 256 && (plane == 0 || plane == 2)) ? (ushort_t)0x3F80 : (ushort_t)0;
    dst[(size_t)tok * PK + c] = val;
}

// ---------------------------------------------------------------------------
// proj_mfma: 4 projections, pre-split weights, 3-term split MFMA
// grid 256: proj = bx>>6, mt = (bx>>2)&15, ft = bx&3
// ---------------------------------------------------------------------------
__global__ __launch_bounds__(256) void proj_mfma(
    const float* __restrict__ x, const float* __restrict__ y,
    const ushort_t* __restrict__ whi, const ushort_t* __restrict__ wlo,
    const float* __restrict__ m1b, const float* __restrict__ m2b,
    const float* __restrict__ hb,  const float* __restrict__ tb,
    ushort_t* __restrict__ h1hi, ushort_t* __restrict__ h1lo,
    ushort_t* __restrict__ t1hi, ushort_t* __restrict__ t1lo,
    float* __restrict__ headf, float* __restrict__ tailf)
{
    const int bx = blockIdx.x;
    const int proj = bx >> 6;
    const int mt = (bx >> 2) & 15;
    const int ft = bx & 3;
    const int wave = threadIdx.x >> 6, L = threadIdx.x & 63;
    const int quad = L >> 4, l16 = L & 15;
    const int m0w = mt * 64 + wave * 16;
    const int f0 = ft * 64;

    const float* src  = (proj == 1) ? y : x;
    const float* bias = (proj == 0) ? m1b : (proj == 1) ? m2b : (proj == 2) ? hb : tb;

    const float* arow = src + (size_t)(m0w + l16) * HID + quad * 8;
    const size_t wbase = (size_t)proj * BIAF * HID;

    floatx4 acc[4];
    #pragma unroll
    for (int nf = 0; nf < 4; ++nf)
        #pragma unroll
        for (int r = 0; r < 4; ++r) acc[nf][r] = 0.f;

    for (int k0 = 0; k0 < HID; k0 += 32) {
        float av[8];
        *(float4*)&av[0] = *(const float4*)(arow + k0);
        *(float4*)&av[4] = *(const float4*)(arow + k0 + 4);
        short8 ahi, alo;
        split8(av, ahi, alo);
        #pragma unroll
        for (int nf = 0; nf < 4; ++nf) {
            size_t boff = wbase + (size_t)(f0 + nf * 16 + l16) * HID + quad * 8 + k0;
            short8 bhi = *(const short8*)(whi + boff);
            short8 blo = *(const short8*)(wlo + boff);
            acc[nf] = MFMA16(ahi, bhi, acc[nf]);
            acc[nf] = MFMA16(alo, bhi, acc[nf]);
            acc[nf] = MFMA16(ahi, blo, acc[nf]);
        }
    }

    #pragma unroll
    for (int nf = 0; nf < 4; ++nf) {
        int feat = f0 + nf * 16 + l16;
        float bv = bias[feat];
        #pragma unroll
        for (int r = 0; r < 4; ++r) {
            int tok = m0w + quad * 4 + r;
            float v = acc[nf][r] + bv;
            if (proj == 0) {
                float g = 0.5f * v * (1.0f + erff(v * 0.70710678118654752f));
                ushort_t h = f2bf(g);
                h1hi[(size_t)tok * PK + feat] = h;
                h1lo[(size_t)tok * PK + feat] = f2bf(g - bf2f(h));
            } else if (proj == 1) {
                float g = 0.5f * v * (1.0f + erff(v * 0.70710678118654752f));
                ushort_t h = f2bf(g);
                t1hi[(size_t)tok * PK + feat] = h;
                t1lo[(size_t)tok * PK + feat] = f2bf(g - bf2f(h));
            } else if (proj == 2) {
                headf[(size_t)tok * 256 + feat] = (v >= 0.f) ? v : 0.01f * v;
            } else {
                tailf[(size_t)tok * 256 + feat] = (v >= 0.f) ? v : 0.01f * v;
            }
        }
    }
}

// ---------------------------------------------------------------------------
// hk[b][k][m] = dot(headf[tok], Wh[k]) + Wh[k][256]; tk likewise with Wt
// ---------------------------------------------------------------------------
__global__ __launch_bounds__(256) void hk_tk_kernel(
    const float* __restrict__ headf, const float* __restrict__ tailf,
    const float* __restrict__ W,
    float* __restrict__ hk, float* __restrict__ tk)
{
    int p = blockIdx.x * 256 + threadIdx.x;  // 32768 items
    int which = p >> 14;                     // 0=hk, 1=tk
    int idx = p & 16383;
    int tok = idx >> 4;
    int k = idx & 15;
    if (k >= CLS) return;
    const float* row = (which ? tailf : headf) + (size_t)tok * 256;
    const float* wr = W + (size_t)k * HSZ + (which ? DD : 0);
    float acc = 0.f;
    for (int f4 = 0; f4 < 64; ++f4) {
        float4 rv = *(const float4*)(row + f4 * 4);
        acc += rv.x * wr[f4*4] + rv.y * wr[f4*4+1] + rv.z * wr[f4*4+2] + rv.w * wr[f4*4+3];
    }
    acc += wr[256];
    float* dst = which ? tk : hk;
    dst[(size_t)(tok >> 9) * CLS * NDIM + (size_t)k * NDIM + (tok & 511)] = acc;
}

// ---------------------------------------------------------------------------
// sk[k][d] = sum_h size_emb[d][h] * Ws[k][h]
// ---------------------------------------------------------------------------
__global__ void sk_kernel(const float* __restrict__ semb, const float* __restrict__ W,
                          float* __restrict__ sk)
{
    int idx = blockIdx.x * 256 + threadIdx.x;
    if (idx < CLS * NPOS) {
        int k = idx / NPOS, d = idx % NPOS;
        float acc = 0.f;
        for (int h = 0; h < SDIM; ++h)
            acc += semb[d*SDIM + h] * W[k*HSZ + 2*DD + h];
        sk[idx] = acc;
    }
}

// ---------------------------------------------------------------------------
// mb_tile: A[bk][m][j] = sum_i h1[b][m][i] * biafW[k][i][j]   (2-term on h1)
// 128x128 tile, LDS-staged. grid (3 jt, 4 mt, 28 bk).
// ---------------------------------------------------------------------------
__global__ __launch_bounds__(256) void mb_tile(
    const ushort_t* __restrict__ h1hi, const ushort_t* __restrict__ h1lo,
    const ushort_t* __restrict__ packW,
    ushort_t* __restrict__ Ab)
{
    __shared__ ushort_t lds[3 * 128 * LDW];   // Ahi, Alo, B = 30720 B
    ushort_t* Ahi = lds;
    ushort_t* Alo = lds + 128 * LDW;
    ushort_t* Bt  = lds + 2 * 128 * LDW;

    const int jt = blockIdx.x, mt = blockIdx.y, bk = blockIdx.z;
    const int b = bk / CLS, k = bk % CLS;
    const int tid = threadIdx.x;
    const int wave = tid >> 6, L = tid & 63;
    const int quad = L >> 4, l16 = L & 15;
    const int m0 = mt * 128;
    const int j0 = jt * 128;
    const int wm = (wave >> 1) * 64;   // wave quadrant row offset
    const int wn = (wave & 1) * 64;    // wave quadrant col offset

    const ushort_t* gA_hi = h1hi + (size_t)(b * NDIM + m0) * PK;
    const ushort_t* gA_lo = h1lo + (size_t)(b * NDIM + m0) * PK;
    const ushort_t* gB    = packW + ((size_t)k * PJ + j0) * PK;

    floatx4 acc[4][4];
    #pragma unroll
    for (int mi = 0; mi < 4; ++mi)
        #pragma unroll
        for (int ni = 0; ni < 4; ++ni)
            #pragma unroll
            for (int r = 0; r < 4; ++r) acc[mi][ni][r] = 0.f;

    for (int k0 = 0; k0 < PK; k0 += 32) {
        stage_tile(gA_hi + k0, PK, Ahi, tid);
        stage_tile(gA_lo + k0, PK, Alo, tid);
        stage_tile(gB + k0, PK, Bt, tid);
        __syncthreads();
        short8 ahi[4], alo[4], bb[4];
        #pragma unroll
        for (int i = 0; i < 4; ++i) {
            ahi[i] = *(const short8*)(Ahi + (wm + i * 16 + l16) * LDW + quad * 8);
            alo[i] = *(const short8*)(Alo + (wm + i * 16 + l16) * LDW + quad * 8);
            bb[i]  = *(const short8*)(Bt  + (wn + i * 16 + l16) * LDW + quad * 8);
        }
        #pragma unroll
        for (int mi = 0; mi < 4; ++mi)
            #pragma unroll
            for (int ni = 0; ni < 4; ++ni) {
                acc[mi][ni] = MFMA16(ahi[mi], bb[ni], acc[mi][ni]);
                acc[mi][ni] = MFMA16(alo[mi], bb[ni], acc[mi][ni]);
            }
        __syncthreads();
    }

    ushort_t* Aout = Ab + (size_t)bk * NDIM * PK;
    #pragma unroll
    for (int mi = 0; mi < 4; ++mi) {
        #pragma unroll
        for (int r = 0; r < 4; ++r) {
            int row = m0 + wm + mi * 16 + quad * 4 + r;
            #pragma unroll
            for (int ni = 0; ni < 4; ++ni) {
                int col = j0 + wn + ni * 16 + l16;
                if (col < PK) Aout[(size_t)row * PK + col] = f2bf(acc[mi][ni][r]);
            }
        }
    }
}

// ---------------------------------------------------------------------------
// mo_tile: out[bk][m][n] = sum_j A[bk][m][j]*t1[b][n][j] + hk + tk + sk
// 128x128 tile, LDS-staged. grid (4 nt, 4 mt, 28 bk).
// ---------------------------------------------------------------------------
__global__ __launch_bounds__(256) void mo_tile(
    const ushort_t* __restrict__ Ab,
    const ushort_t* __restrict__ t1hi, const ushort_t* __restrict__ t1lo,
    const float* __restrict__ hk, const float* __restrict__ tk,
    const float* __restrict__ sk,
    float* __restrict__ out)
{
    __shared__ ushort_t lds[3 * 128 * LDW];   // A, Bhi, Blo
    __shared__ float skr[NPOS];
    ushort_t* At  = lds;
    ushort_t* Bhi = lds + 128 * LDW;
    ushort_t* Blo = lds + 2 * 128 * LDW;

    const int nt = blockIdx.x, mt = blockIdx.y, bk = blockIdx.z;
    const int b = bk / CLS, k = bk % CLS;
    const int tid = threadIdx.x;
    if (tid < NPOS) skr[tid] = sk[k * NPOS + tid];
    const int wave = tid >> 6, L = tid & 63;
    const int quad = L >> 4, l16 = L & 15;
    const int m0 = mt * 128;
    const int n0 = nt * 128;
    const int wm = (wave >> 1) * 64;
    const int wn = (wave & 1) * 64;

    const ushort_t* gA  = Ab + ((size_t)bk * NDIM + m0) * PK;
    const ushort_t* gBh = t1hi + (size_t)(b * NDIM + n0) * PK;
    const ushort_t* gBl = t1lo + (size_t)(b * NDIM + n0) * PK;

    floatx4 acc[4][4];
    #pragma unroll
    for (int mi = 0; mi < 4; ++mi)
        #pragma unroll
        for (int ni = 0; ni < 4; ++ni)
            #pragma unroll
            for (int r = 0; r < 4; ++r) acc[mi][ni][r] = 0.f;

    for (int k0 = 0; k0 < PK; k0 += 32) {
        stage_tile(gA + k0, PK, At, tid);
        stage_tile(gBh + k0, PK, Bhi, tid);
        stage_tile(gBl + k0, PK, Blo, tid);
        __syncthreads();
        short8 a[4], bh[4], bl[4];
        #pragma unroll
        for (int i = 0; i < 4; ++i) {
            a[i]  = *(const short8*)(At  + (wm + i * 16 + l16) * LDW + quad * 8);
            bh[i] = *(const short8*)(Bhi + (wn + i * 16 + l16) * LDW + quad * 8);
            bl[i] = *(const short8*)(Blo + (wn + i * 16 + l16) * LDW + quad * 8);
        }
        #pragma unroll
        for (int mi = 0; mi < 4; ++mi)
            #pragma unroll
            for (int ni = 0; ni < 4; ++ni) {
                acc[mi][ni] = MFMA16(a[mi], bh[ni], acc[mi][ni]);
                acc[mi][ni] = MFMA16(a[mi], bl[ni], acc[mi][ni]);
            }
        __syncthreads();
    }

    const size_t obase = (size_t)bk * NDIM;
    #pragma unroll
    for (int mi = 0; mi < 4; ++mi) {
        #pragma unroll
        for (int r = 0; r < 4; ++r) {
            int row = m0 + wm + mi * 16 + quad * 4 + r;
            float hv = hk[obase + row];
            #pragma unroll
            for (int ni = 0; ni < 4; ++ni) {
                int col = n0 + wn + ni * 16 + l16;
                int d = col - row; d = d < -15 ? -15 : (d > 14 ? 14 : d); d += 15;
                out[(obase + row) * NDIM + col] = acc[mi][ni][r] + hv + tk[obase + col] + skr[d];
            }
        }
    }
}

// ---------------------------------------------------------------------------
extern "C" void kernel_launch(void* const* d_in, const int* in_sizes, int n_in,
                              void* d_out, int out_size, void* d_ws, size_t ws_size,
                              hipStream_t stream) {
    const float* x    = (const float*)d_in[0];
    const float* y    = (const float*)d_in[1];
    // d_in[2] = z : unused
    const float* m1w  = (const float*)d_in[3];
    const float* m1b  = (const float*)d_in[4];
    const float* m2w  = (const float*)d_in[5];
    const float* m2b  = (const float*)d_in[6];
    const float* hw   = (const float*)d_in[7];
    const float* hb   = (const float*)d_in[8];
    const float* tw   = (const float*)d_in[9];
    const float* tb   = (const float*)d_in[10];
    const float* biafW= (const float*)d_in[11];
    const float* W    = (const float*)d_in[12];
    const float* semb = (const float*)d_in[13];

    char* p = (char*)d_ws;
    float* hk   = (float*)p;                    p += 57344;
    float* tk   = (float*)p;                    p += 57344;
    float* skp  = (float*)p;                    p += 2048;
    float* headf= (float*)p;                    p += 1048576;
    float* tailf= (float*)p;                    p += 1048576;
    ushort_t* h1hi = (ushort_t*)p;              p += 589824;
    ushort_t* h1lo = (ushort_t*)p;              p += 589824;
    ushort_t* t1hi = (ushort_t*)p;              p += 589824;
    ushort_t* t1lo = (ushort_t*)p;              p += 589824;
    ushort_t* packW= (ushort_t*)p;              p += 3096576;  // 14*384*288*2
    ushort_t* whi  = (ushort_t*)p;              p += 1572864;  // 4*256*768*2
    ushort_t* wlo  = (ushort_t*)p;              p += 1572864;
    ushort_t* Abuf = (ushort_t*)p;              p += 8257536;  // 28*512*288*2

    repack_t<<<dim3(9, 12, CLS), 256, 0, stream>>>(biafW, packW);
    wsplit<<<3072, 256, 0, stream>>>(m1w, m2w, hw, tw, whi, wlo);
    fill_pads<<<512, 256, 0, stream>>>(h1hi, h1lo, t1hi, t1lo);
    proj_mfma<<<256, 256, 0, stream>>>(x, y, whi, wlo, m1b, m2b, hb, tb,
                                       h1hi, h1lo, t1hi, t1lo, headf, tailf);
    hk_tk_kernel<<<128, 256, 0, stream>>>(headf, tailf, W, hk, tk);
    sk_kernel<<<2, 256, 0, stream>>>(semb, W, skp);
    mb_tile<<<dim3(3, 4, BDIM*CLS), 256, 0, stream>>>(h1hi, h1lo, packW, Abuf);
    mo_tile<<<dim3(4, 4, BDIM*CLS), 256, 0, stream>>>(Abuf, t1hi, t1lo, hk, tk, skp,
                                                      (float*)d_out);
}

// Round 7
// 209.776 us; speedup vs baseline: 1.2370x; 1.0223x over previous
//
#include <hip/hip_runtime.h>
#include <hip/hip_bf16.h>
#include <math.h>
#include <stdint.h>

#define BDIM 2
#define NDIM 512
#define HID 768
#define BIAF 256
#define CLS 14
#define DD 257   // BIAF+1
#define NPOS 30
#define SDIM 25
#define HSZ 539  // 2*257+25
#define PK 288   // padded contraction length (i and j), 9*32
#define PJ 384   // packW j-rows padding

typedef unsigned short ushort_t;
typedef __attribute__((ext_vector_type(8))) short short8;   // 8 bf16
typedef __attribute__((ext_vector_type(4))) float floatx4;  // 4 f32

#define MFMA16(a, b, c) __builtin_amdgcn_mfma_f32_16x16x32_bf16((a), (b), (c), 0, 0, 0)

__device__ inline float bf2f(ushort_t u) {
    union { unsigned int i; float f; } c; c.i = ((unsigned)u) << 16; return c.f;
}
__device__ inline ushort_t f2bf(float f) {
    __hip_bfloat16 h = __float2bfloat16(f);
    return *(ushort_t*)&h;
}

// async global->LDS, 16B per lane. LDS dest = wave-uniform base + lane*16.
__device__ inline void glds16(const ushort_t* g, const ushort_t* l) {
    __builtin_amdgcn_global_load_lds(
        (const __attribute__((address_space(1))) unsigned int*)(unsigned long long)(uintptr_t)g,
        (__attribute__((address_space(3))) unsigned int*)(unsigned int)(uintptr_t)l,
        16, 0, 0);
}

// ---------------------------------------------------------------------------
// repack_t: packW[k][j][i] = bf16(biafW[k][i][j]), zero-padded to PJ x PK
// ---------------------------------------------------------------------------
__global__ __launch_bounds__(256) void repack_t(
    const float* __restrict__ biafW, ushort_t* __restrict__ packW)
{
    __shared__ float tile[32][33];
    const int i0 = blockIdx.x * 32;
    const int j0 = blockIdx.y * 32;
    const int k  = blockIdx.z;
    const int r8 = threadIdx.x >> 5;   // 0..7
    const int c  = threadIdx.x & 31;
    #pragma unroll
    for (int rr = 0; rr < 4; ++rr) {
        int r = rr * 8 + r8;
        int gi = i0 + r, gj = j0 + c;
        tile[r][c] = (gi < DD && gj < DD) ? biafW[((size_t)k * DD + gi) * DD + gj] : 0.f;
    }
    __syncthreads();
    #pragma unroll
    for (int rr = 0; rr < 4; ++rr) {
        int jr = rr * 8 + r8;
        packW[((size_t)k * PJ + (j0 + jr)) * PK + i0 + c] = f2bf(tile[c][jr]);
    }
}

// ---------------------------------------------------------------------------
// wsplit: hi/lo bf16 planes of the 4 projection weight matrices
// ---------------------------------------------------------------------------
__global__ __launch_bounds__(256) void wsplit(
    const float* __restrict__ m1w, const float* __restrict__ m2w,
    const float* __restrict__ hw,  const float* __restrict__ tw,
    ushort_t* __restrict__ whi, ushort_t* __restrict__ wlo)
{
    int idx = blockIdx.x * 256 + threadIdx.x;      // 786432 items
    int mat = idx / (BIAF * HID);
    int rem = idx % (BIAF * HID);
    const float* src = (mat == 0) ? m1w : (mat == 1) ? m2w : (mat == 2) ? hw : tw;
    float v = src[rem];
    ushort_t h = f2bf(v);
    whi[idx] = h;
    wlo[idx] = f2bf(v - bf2f(h));
}

// ---------------------------------------------------------------------------
// xysplit: hi/lo bf16 planes of x and y (each 1024x768)
// ---------------------------------------------------------------------------
__global__ __launch_bounds__(256) void xysplit(
    const float* __restrict__ x, const float* __restrict__ y,
    ushort_t* __restrict__ xhi, ushort_t* __restrict__ xlo,
    ushort_t* __restrict__ yhi, ushort_t* __restrict__ ylo)
{
    int idx = blockIdx.x * 256 + threadIdx.x;      // 2*786432 items
    int which = idx >= (BDIM*NDIM*HID);
    int rem = which ? idx - BDIM*NDIM*HID : idx;
    float v = (which ? y : x)[rem];
    ushort_t h = f2bf(v);
    (which ? yhi : xhi)[rem] = h;
    (which ? ylo : xlo)[rem] = f2bf(v - bf2f(h));
}

// ---------------------------------------------------------------------------
// fill pad columns of h1/t1 hi/lo planes: col 256 = 1.0(hi)/0(lo), 257..287 = 0
// ---------------------------------------------------------------------------
__global__ void fill_pads(ushort_t* __restrict__ h1hi, ushort_t* __restrict__ h1lo,
                          ushort_t* __restrict__ t1hi, ushort_t* __restrict__ t1lo) {
    int idx = blockIdx.x * 256 + threadIdx.x;          // 131072 items
    int plane = idx >> 15;                             // 0..3
    int tok = (idx >> 5) & 1023;
    int c   = 256 + (idx & 31);
    ushort_t* dst = (plane == 0) ? h1hi : (plane == 1) ? h1lo : (plane == 2) ? t1hi : t1lo;
    ushort_t val = (c == 256 && (plane == 0 || plane == 2)) ? (ushort_t)0x3F80 : (ushort_t)0;
    dst[(size_t)tok * PK + c] = val;
}

// ---------------------------------------------------------------------------
// proj_mfma v3: direct-load MFMA, pre-split operands, 3-term.
// grid (8 ft, 16 mt, 4 proj); wave tile = 16 tokens x 32 features.
// ---------------------------------------------------------------------------
__global__ __launch_bounds__(256) void proj_mfma(
    const ushort_t* __restrict__ xhi, const ushort_t* __restrict__ xlo,
    const ushort_t* __restrict__ yhi, const ushort_t* __restrict__ ylo,
    const ushort_t* __restrict__ whi, const ushort_t* __restrict__ wlo,
    const float* __restrict__ m1b, const float* __restrict__ m2b,
    const float* __restrict__ hb,  const float* __restrict__ tb,
    ushort_t* __restrict__ h1hi, ushort_t* __restrict__ h1lo,
    ushort_t* __restrict__ t1hi, ushort_t* __restrict__ t1lo,
    float* __restrict__ headf, float* __restrict__ tailf)
{
    const int ft = blockIdx.x;       // 0..7  -> 32 features
    const int mt = blockIdx.y;       // 0..15 -> 64 tokens
    const int proj = blockIdx.z;     // 0..3
    const int wave = threadIdx.x >> 6, L = threadIdx.x & 63;
    const int quad = L >> 4, l16 = L & 15;
    const int tok0 = mt * 64 + wave * 16;
    const int f0 = ft * 32;

    const ushort_t* ahi_p = (proj == 1) ? yhi : xhi;
    const ushort_t* alo_p = (proj == 1) ? ylo : xlo;
    const float* bias = (proj == 0) ? m1b : (proj == 1) ? m2b : (proj == 2) ? hb : tb;

    const size_t aoff = (size_t)(tok0 + l16) * HID + quad * 8;
    const size_t wbase = (size_t)proj * BIAF * HID;
    const size_t b0 = wbase + (size_t)(f0 + l16) * HID + quad * 8;
    const size_t b1 = wbase + (size_t)(f0 + 16 + l16) * HID + quad * 8;

    floatx4 acc0 = {0.f, 0.f, 0.f, 0.f}, acc1 = {0.f, 0.f, 0.f, 0.f};
    #pragma unroll 4
    for (int k0 = 0; k0 < HID; k0 += 32) {
        short8 ah  = *(const short8*)(ahi_p + aoff + k0);
        short8 al  = *(const short8*)(alo_p + aoff + k0);
        short8 bh0 = *(const short8*)(whi + b0 + k0);
        short8 bl0 = *(const short8*)(wlo + b0 + k0);
        short8 bh1 = *(const short8*)(whi + b1 + k0);
        short8 bl1 = *(const short8*)(wlo + b1 + k0);
        acc0 = MFMA16(ah, bh0, acc0);
        acc1 = MFMA16(ah, bh1, acc1);
        acc0 = MFMA16(al, bh0, acc0);
        acc1 = MFMA16(al, bh1, acc1);
        acc0 = MFMA16(ah, bl0, acc0);
        acc1 = MFMA16(ah, bl1, acc1);
    }

    #pragma unroll
    for (int nf = 0; nf < 2; ++nf) {
        floatx4 a = nf ? acc1 : acc0;
        int feat = f0 + nf * 16 + l16;
        float bv = bias[feat];
        #pragma unroll
        for (int r = 0; r < 4; ++r) {
            int tok = tok0 + quad * 4 + r;
            float v = a[r] + bv;
            if (proj <= 1) {
                float g = 0.5f * v * (1.0f + erff(v * 0.70710678118654752f));
                ushort_t h = f2bf(g);
                ushort_t lo = f2bf(g - bf2f(h));
                if (proj == 0) { h1hi[(size_t)tok * PK + feat] = h; h1lo[(size_t)tok * PK + feat] = lo; }
                else           { t1hi[(size_t)tok * PK + feat] = h; t1lo[(size_t)tok * PK + feat] = lo; }
            } else {
                float lv = (v >= 0.f) ? v : 0.01f * v;
                if (proj == 2) headf[(size_t)tok * 256 + feat] = lv;
                else           tailf[(size_t)tok * 256 + feat] = lv;
            }
        }
    }
}

// ---------------------------------------------------------------------------
// hk[b][k][m] = dot(headf[tok], Wh[k]) + Wh[k][256]; tk likewise with Wt
// ---------------------------------------------------------------------------
__global__ __launch_bounds__(256) void hk_tk_kernel(
    const float* __restrict__ headf, const float* __restrict__ tailf,
    const float* __restrict__ W,
    float* __restrict__ hk, float* __restrict__ tk)
{
    int p = blockIdx.x * 256 + threadIdx.x;  // 32768 items
    int which = p >> 14;                     // 0=hk, 1=tk
    int idx = p & 16383;
    int tok = idx >> 4;
    int k = idx & 15;
    if (k >= CLS) return;
    const float* row = (which ? tailf : headf) + (size_t)tok * 256;
    const float* wr = W + (size_t)k * HSZ + (which ? DD : 0);
    float acc = 0.f;
    for (int f4 = 0; f4 < 64; ++f4) {
        float4 rv = *(const float4*)(row + f4 * 4);
        acc += rv.x * wr[f4*4] + rv.y * wr[f4*4+1] + rv.z * wr[f4*4+2] + rv.w * wr[f4*4+3];
    }
    acc += wr[256];
    float* dst = which ? tk : hk;
    dst[(size_t)(tok >> 9) * CLS * NDIM + (size_t)k * NDIM + (tok & 511)] = acc;
}

// ---------------------------------------------------------------------------
// sk[k][d] = sum_h size_emb[d][h] * Ws[k][h]
// ---------------------------------------------------------------------------
__global__ void sk_kernel(const float* __restrict__ semb, const float* __restrict__ W,
                          float* __restrict__ sk)
{
    int idx = blockIdx.x * 256 + threadIdx.x;
    if (idx < CLS * NPOS) {
        int k = idx / NPOS, d = idx % NPOS;
        float acc = 0.f;
        for (int h = 0; h < SDIM; ++h)
            acc += semb[d*SDIM + h] * W[k*HSZ + 2*DD + h];
        sk[idx] = acc;
    }
}

// ---------------------------------------------------------------------------
// mb_tile v3: A[bk][m][j] = sum_i h1[b][m][i] * biafW[k][i][j]  (2-term on h1)
// tile 64x96, glds staging. grid (3 jt, 8 mt, 28 bk) = 672 blocks.
// ---------------------------------------------------------------------------
__global__ __launch_bounds__(256) void mb_tile(
    const ushort_t* __restrict__ h1hi, const ushort_t* __restrict__ h1lo,
    const ushort_t* __restrict__ packW,
    ushort_t* __restrict__ Ab)
{
    __shared__ ushort_t Ah[64 * 32];   // 4KB
    __shared__ ushort_t Al[64 * 32];   // 4KB
    __shared__ ushort_t Bt[96 * 32];   // 6KB
    const int jt = blockIdx.x, mt = blockIdx.y, bk = blockIdx.z;
    const int b = bk / CLS, k = bk % CLS;
    const int tid = threadIdx.x;
    const int wave = tid >> 6, L = tid & 63;
    const int quad = L >> 4, l16 = L & 15;
    const int lrow = L >> 2, lq = L & 3;
    const int m0 = mt * 64, j0 = jt * 96;
    const int wm = (wave >> 1) * 32, wj = (wave & 1) * 48;

    const ushort_t* gAh = h1hi + (size_t)(b * NDIM + m0) * PK;
    const ushort_t* gAl = h1lo + (size_t)(b * NDIM + m0) * PK;
    const ushort_t* gB  = packW + ((size_t)k * PJ + j0) * PK;

    floatx4 acc[2][3];
    #pragma unroll
    for (int mi = 0; mi < 2; ++mi)
        #pragma unroll
        for (int ni = 0; ni < 3; ++ni)
            #pragma unroll
            for (int r = 0; r < 4; ++r) acc[mi][ni][r] = 0.f;

    for (int k0 = 0; k0 < PK; k0 += 32) {
        // 14 x 1KB segments: 4 Ah, 4 Al, 6 Bt
        for (int s = wave; s < 14; s += 4) {
            const ushort_t* g; const ushort_t* l;
            if (s < 4)      { l = Ah + s * 512;       g = gAh + (size_t)(s * 16 + lrow) * PK + k0 + lq * 8; }
            else if (s < 8) { l = Al + (s - 4) * 512; g = gAl + (size_t)((s - 4) * 16 + lrow) * PK + k0 + lq * 8; }
            else            { l = Bt + (s - 8) * 512; g = gB  + (size_t)((s - 8) * 16 + lrow) * PK + k0 + lq * 8; }
            glds16(g, l);
        }
        __syncthreads();
        short8 ah[2], al[2], bb[3];
        #pragma unroll
        for (int mi = 0; mi < 2; ++mi) {
            ah[mi] = *(const short8*)(Ah + (wm + mi * 16 + l16) * 32 + quad * 8);
            al[mi] = *(const short8*)(Al + (wm + mi * 16 + l16) * 32 + quad * 8);
        }
        #pragma unroll
        for (int ni = 0; ni < 3; ++ni)
            bb[ni] = *(const short8*)(Bt + (wj + ni * 16 + l16) * 32 + quad * 8);
        #pragma unroll
        for (int mi = 0; mi < 2; ++mi)
            #pragma unroll
            for (int ni = 0; ni < 3; ++ni) {
                acc[mi][ni] = MFMA16(ah[mi], bb[ni], acc[mi][ni]);
                acc[mi][ni] = MFMA16(al[mi], bb[ni], acc[mi][ni]);
            }
        __syncthreads();
    }

    ushort_t* Aout = Ab + (size_t)bk * NDIM * PK;
    #pragma unroll
    for (int mi = 0; mi < 2; ++mi) {
        #pragma unroll
        for (int r = 0; r < 4; ++r) {
            int row = m0 + wm + mi * 16 + quad * 4 + r;
            #pragma unroll
            for (int ni = 0; ni < 3; ++ni) {
                int col = j0 + wj + ni * 16 + l16;
                Aout[(size_t)row * PK + col] = f2bf(acc[mi][ni][r]);
            }
        }
    }
}

// ---------------------------------------------------------------------------
// mo_tile v3: out[bk][m][n] = sum_j A[bk][m][j]*t1[b][n][j] + hk + tk + sk
// tile 64x128, glds staging. grid (4 nt, 8 mt, 28 bk) = 896 blocks.
// ---------------------------------------------------------------------------
__global__ __launch_bounds__(256) void mo_tile(
    const ushort_t* __restrict__ Ab,
    const ushort_t* __restrict__ t1hi, const ushort_t* __restrict__ t1lo,
    const float* __restrict__ hk, const float* __restrict__ tk,
    const float* __restrict__ sk,
    float* __restrict__ out)
{
    __shared__ ushort_t At[64 * 32];    // 4KB
    __shared__ ushort_t Bh[128 * 32];   // 8KB
    __shared__ ushort_t Bl[128 * 32];   // 8KB
    __shared__ float skr[NPOS];
    const int nt = blockIdx.x, mt = blockIdx.y, bk = blockIdx.z;
    const int b = bk / CLS, k = bk % CLS;
    const int tid = threadIdx.x;
    if (tid < NPOS) skr[tid] = sk[k * NPOS + tid];
    const int wave = tid >> 6, L = tid & 63;
    const int quad = L >> 4, l16 = L & 15;
    const int lrow = L >> 2, lq = L & 3;
    const int m0 = mt * 64, n0 = nt * 128;
    const int wm = (wave >> 1) * 32, wn = (wave & 1) * 64;

    const ushort_t* gA  = Ab + ((size_t)bk * NDIM + m0) * PK;
    const ushort_t* gBh = t1hi + (size_t)(b * NDIM + n0) * PK;
    const ushort_t* gBl = t1lo + (size_t)(b * NDIM + n0) * PK;

    floatx4 acc[2][4];
    #pragma unroll
    for (int mi = 0; mi < 2; ++mi)
        #pragma unroll
        for (int ni = 0; ni < 4; ++ni)
            #pragma unroll
            for (int r = 0; r < 4; ++r) acc[mi][ni][r] = 0.f;

    for (int k0 = 0; k0 < PK; k0 += 32) {
        // 20 x 1KB segments: 4 At, 8 Bh, 8 Bl
        for (int s = wave; s < 20; s += 4) {
            const ushort_t* g; const ushort_t* l;
            if (s < 4)       { l = At + s * 512;        g = gA  + (size_t)(s * 16 + lrow) * PK + k0 + lq * 8; }
            else if (s < 12) { l = Bh + (s - 4) * 512;  g = gBh + (size_t)((s - 4) * 16 + lrow) * PK + k0 + lq * 8; }
            else             { l = Bl + (s - 12) * 512; g = gBl + (size_t)((s - 12) * 16 + lrow) * PK + k0 + lq * 8; }
            glds16(g, l);
        }
        __syncthreads();
        short8 a[2], bh[4], bl[4];
        #pragma unroll
        for (int mi = 0; mi < 2; ++mi)
            a[mi] = *(const short8*)(At + (wm + mi * 16 + l16) * 32 + quad * 8);
        #pragma unroll
        for (int ni = 0; ni < 4; ++ni) {
            bh[ni] = *(const short8*)(Bh + (wn + ni * 16 + l16) * 32 + quad * 8);
            bl[ni] = *(const short8*)(Bl + (wn + ni * 16 + l16) * 32 + quad * 8);
        }
        #pragma unroll
        for (int mi = 0; mi < 2; ++mi)
            #pragma unroll
            for (int ni = 0; ni < 4; ++ni) {
                acc[mi][ni] = MFMA16(a[mi], bh[ni], acc[mi][ni]);
                acc[mi][ni] = MFMA16(a[mi], bl[ni], acc[mi][ni]);
            }
        __syncthreads();
    }

    const size_t obase = (size_t)bk * NDIM;
    #pragma unroll
    for (int mi = 0; mi < 2; ++mi) {
        #pragma unroll
        for (int r = 0; r < 4; ++r) {
            int row = m0 + wm + mi * 16 + quad * 4 + r;
            float hv = hk[obase + row];
            #pragma unroll
            for (int ni = 0; ni < 4; ++ni) {
                int col = n0 + wn + ni * 16 + l16;
                int d = col - row; d = d < -15 ? -15 : (d > 14 ? 14 : d); d += 15;
                out[(obase + row) * NDIM + col] = acc[mi][ni][r] + hv + tk[obase + col] + skr[d];
            }
        }
    }
}

// ---------------------------------------------------------------------------
extern "C" void kernel_launch(void* const* d_in, const int* in_sizes, int n_in,
                              void* d_out, int out_size, void* d_ws, size_t ws_size,
                              hipStream_t stream) {
    const float* x    = (const float*)d_in[0];
    const float* y    = (const float*)d_in[1];
    // d_in[2] = z : unused
    const float* m1w  = (const float*)d_in[3];
    const float* m1b  = (const float*)d_in[4];
    const float* m2w  = (const float*)d_in[5];
    const float* m2b  = (const float*)d_in[6];
    const float* hw   = (const float*)d_in[7];
    const float* hb   = (const float*)d_in[8];
    const float* tw   = (const float*)d_in[9];
    const float* tb   = (const float*)d_in[10];
    const float* biafW= (const float*)d_in[11];
    const float* W    = (const float*)d_in[12];
    const float* semb = (const float*)d_in[13];

    char* p = (char*)d_ws;
    float* hk   = (float*)p;                    p += 57344;
    float* tk   = (float*)p;                    p += 57344;
    float* skp  = (float*)p;                    p += 2048;
    float* headf= (float*)p;                    p += 1048576;
    float* tailf= (float*)p;                    p += 1048576;
    ushort_t* h1hi = (ushort_t*)p;              p += 589824;
    ushort_t* h1lo = (ushort_t*)p;              p += 589824;
    ushort_t* t1hi = (ushort_t*)p;              p += 589824;
    ushort_t* t1lo = (ushort_t*)p;              p += 589824;
    ushort_t* packW= (ushort_t*)p;              p += 3096576;  // 14*384*288*2
    ushort_t* whi  = (ushort_t*)p;              p += 1572864;  // 4*256*768*2
    ushort_t* wlo  = (ushort_t*)p;              p += 1572864;
    ushort_t* Abuf = (ushort_t*)p;              p += 8257536;  // 28*512*288*2
    ushort_t* xhi  = (ushort_t*)p;              p += 1572864;  // 1024*768*2
    ushort_t* xlo  = (ushort_t*)p;              p += 1572864;
    ushort_t* yhi  = (ushort_t*)p;              p += 1572864;
    ushort_t* ylo  = (ushort_t*)p;              p += 1572864;

    repack_t<<<dim3(9, 12, CLS), 256, 0, stream>>>(biafW, packW);
    wsplit<<<3072, 256, 0, stream>>>(m1w, m2w, hw, tw, whi, wlo);
    xysplit<<<6144, 256, 0, stream>>>(x, y, xhi, xlo, yhi, ylo);
    fill_pads<<<512, 256, 0, stream>>>(h1hi, h1lo, t1hi, t1lo);
    proj_mfma<<<dim3(8, 16, 4), 256, 0, stream>>>(xhi, xlo, yhi, ylo, whi, wlo,
                                                  m1b, m2b, hb, tb,
                                                  h1hi, h1lo, t1hi, t1lo, headf, tailf);
    hk_tk_kernel<<<128, 256, 0, stream>>>(headf, tailf, W, hk, tk);
    sk_kernel<<<2, 256, 0, stream>>>(semb, W, skp);
    mb_tile<<<dim3(3, 8, BDIM*CLS), 256, 0, stream>>>(h1hi, h1lo, packW, Abuf);
    mo_tile<<<dim3(4, 8, BDIM*CLS), 256, 0, stream>>>(Abuf, t1hi, t1lo, hk, tk, skp,
                                                      (float*)d_out);
}